// Round 14
// baseline (208.680 us; speedup 1.0000x reference)
//
#include <hip/hip_runtime.h>
#include <math.h>

typedef __attribute__((ext_vector_type(8))) short bf16x8;
typedef __attribute__((ext_vector_type(4))) float f32x4;
typedef __attribute__((ext_vector_type(16))) float f32x16;
typedef __attribute__((ext_vector_type(4))) unsigned u32x4;

__device__ inline short f2bf(float f) {
  unsigned u = __builtin_bit_cast(unsigned, f);
  u = u + 0x7fffu + ((u >> 16) & 1u);
  return (short)(u >> 16);
}
__device__ inline float bf2f(short s) {
  return __builtin_bit_cast(float, ((unsigned)(unsigned short)s) << 16);
}
__device__ inline unsigned cvt_pk_bf16(float lo, float hi) {
  unsigned r;
  asm("v_cvt_pk_bf16_f32 %0, %1, %2" : "=v"(r) : "v"(lo), "v"(hi));
  return r;
}

// async global->LDS, 16B per lane. lds base must be wave-uniform.
__device__ inline void gload16(const short* g, const short* l) {
  __builtin_amdgcn_global_load_lds(
      (const __attribute__((address_space(1))) unsigned*)g,
      (__attribute__((address_space(3))) unsigned*)(short*)l, 16, 0, 0);
}

// ---------------- all four weight transposes fp32[K,N] -> bf16[N,K] ---------
__global__ __launch_bounds__(256) void wtrans_all(
    const float* __restrict__ wa, const float* __restrict__ wc,
    const float* __restrict__ wf, const float* __restrict__ wm,
    short* __restrict__ oa, short* __restrict__ oc,
    short* __restrict__ of, short* __restrict__ om) {
  __shared__ float tile[32][33];
  int blk = blockIdx.x;
  const float* in; short* out; int K, N, bx;
  if (blk < 1728)      { in = wa; out = oa; K = 768;  N = 2304; bx = 72; }
  else if (blk < 2304) { blk -= 1728; in = wc; out = oc; K = 768;  N = 768;  bx = 24; }
  else if (blk < 4608) { blk -= 2304; in = wf; out = of; K = 768;  N = 3072; bx = 96; }
  else                 { blk -= 4608; in = wm; out = om; K = 3072; N = 768;  bx = 24; }
  const int n0 = (blk % bx) * 32, k0 = (blk / bx) * 32;
  const int tx = threadIdx.x & 31, ty = threadIdx.x >> 5;
  #pragma unroll
  for (int r = ty; r < 32; r += 8)
    tile[r][tx] = in[(size_t)(k0 + r) * N + n0 + tx];
  __syncthreads();
  #pragma unroll
  for (int r = ty; r < 32; r += 8)
    out[(size_t)(n0 + r) * K + k0 + tx] = f2bf(tile[tx][r]);
}

// ------- merged prep: blocks [0,6144) qprime (+ktab on bh==0); rest vtrans ---
__global__ __launch_bounds__(256) void qv_kernel(
    const short* __restrict__ qkv, short* __restrict__ qpr,
    short* __restrict__ ktab, short* __restrict__ vT) {
  __shared__ short tile[64][65];
  if (blockIdx.x < 6144) {
    const int idx = blockIdx.x * 256 + threadIdx.x;  // 48*1024*32
    const int cc = idx & 31;
    const int row = idx >> 5;            // bh*1024 + i
    const int i = row & 1023, bh = row >> 10;
    const int b = bh / 12, h = bh % 12;
    const float invf = exp2f(-(float)cc * (13.287712379549449f / 32.0f));
    const float ang = (float)i * invf;
    float si, co;
    __sincosf(ang, &si, &co);
    if (bh == 0) {
      ktab[i * 64 + cc]      = f2bf(co);
      ktab[i * 64 + 32 + cc] = f2bf(si);
    }
    const short* q = qkv + (size_t)(b * 1024 + i) * 2304 + h * 64;
    const float qs = bf2f(q[cc]), qc = bf2f(q[32 + cc]);
    qpr[(size_t)row * 64 + cc]      = f2bf(qs * si + qc * co);
    qpr[(size_t)row * 64 + 32 + cc] = f2bf(qc * si - qs * co);
  } else {
    const int blk = blockIdx.x - 6144;
    const int bh = blk >> 4, t0 = (blk & 15) * 64;
    const int b = bh / 12, h = bh % 12;
    const int tx = threadIdx.x & 63, ty = threadIdx.x >> 6;
    const short* src = qkv + (size_t)(b * 1024 + t0) * 2304 + 1536 + h * 64;
    #pragma unroll
    for (int r = ty; r < 64; r += 4)
      tile[r][tx] = src[(size_t)r * 2304 + tx];
    __syncthreads();
    short* dst = vT + (size_t)bh * 64 * 1024 + t0;
    #pragma unroll
    for (int r = ty; r < 64; r += 4)
      dst[(size_t)r * 1024 + tx] = tile[tx][r];
  }
}

// ---------------- LayerNorm fp32 row(768) -> bf16 ----------------
__global__ __launch_bounds__(256) void ln_kernel(
    const float* __restrict__ x, const float* __restrict__ w,
    short* __restrict__ out) {
  const int row = blockIdx.x, tid = threadIdx.x;
  const float* xr = x + (size_t)row * 768;
  float v0 = xr[tid], v1 = xr[tid + 256], v2 = xr[tid + 512];
  float s = v0 + v1 + v2;
  #pragma unroll
  for (int o = 1; o < 64; o <<= 1) s += __shfl_xor(s, o);
  __shared__ float red[8];
  const int wv = tid >> 6;
  if ((tid & 63) == 0) red[wv] = s;
  __syncthreads();
  const float mean = (red[0] + red[1] + red[2] + red[3]) * (1.0f / 768.0f);
  v0 -= mean; v1 -= mean; v2 -= mean;
  float q = v0 * v0 + v1 * v1 + v2 * v2;
  #pragma unroll
  for (int o = 1; o < 64; o <<= 1) q += __shfl_xor(q, o);
  if ((tid & 63) == 0) red[4 + wv] = q;
  __syncthreads();
  const float var = (red[4] + red[5] + red[6] + red[7]) * (1.0f / 768.0f);
  const float inv = 1.0f / sqrtf(var + 1e-5f);
  out[(size_t)row * 768 + tid]       = f2bf(v0 * inv * w[tid]);
  out[(size_t)row * 768 + tid + 256] = f2bf(v1 * inv * w[tid + 256]);
  out[(size_t)row * 768 + tid + 512] = f2bf(v2 * inv * w[tid + 512]);
}

// ======= GEMM: 3-stage ring + T2 XOR chunk-swizzle (conflict-free reads) ====
// C[M,N] = A[M,K] x Bt[N,K], bf16 in, f32 acc. BK=32. nt MUST be %3==0.
// R14: big GEMMs use 64x128 tiles -> 2x grid -> 4+ blocks/CU (grid was the
// occupancy cap at 128x128; intra-step opts R10/R11/R13 all neutral).
// EPI 0: bf16 store  1: f32 out=res+acc  2: bf16 gelu  3: f32 split-K partial
template <int EPI, int BM, int BN>
__global__ __launch_bounds__(256) void gemm3u(
    const short* __restrict__ A, const short* __restrict__ Bt,
    const float* __restrict__ res, float* __restrict__ outF,
    short* __restrict__ outB, int M, int N, int K, int lda, int ldb) {
  __shared__ __align__(16) short As[3][BM * 32];
  __shared__ __align__(16) short Bs[3][BN * 32];
  constexpr int WM = BM / 2, WN = BN / 2;
  constexpr int MI = WM / 16, NJ = WN / 16;
  constexpr int NA = BM / 64, NB = BN / 64;
  constexpr int G = NA + NB;          // gloads per stage per wave
  const int tid = threadIdx.x;
  const int w = tid >> 6, lane = tid & 63;
  // T1 XCD-aware bijective swizzle (x-fastest dispatch order)
  const int gx = gridDim.x, gy = gridDim.y;
  const int nwg = gx * gy * gridDim.z;
  const int lin = blockIdx.x + gx * (blockIdx.y + gy * blockIdx.z);
  const int wg = (lin & 7) * (nwg >> 3) + (lin >> 3);
  const int bxi = wg % gx;
  const int tmp = wg / gx;
  const int byi = tmp % gy, bzi = tmp / gy;
  const int m0 = byi * BM, n0 = bxi * BN;
  const int wm = (w >> 1) * WM, wn = (w & 1) * WN;
  const int lr = lane >> 2;
  // T2: source chunk pre-swizzle  slot -> global chunk (slot ^ s(row))
  const int lc = (((lane & 3) ^ ((lr >> 1) & 3))) * 8;
  if constexpr (EPI == 3) {
    A += (size_t)bzi * K;
    Bt += (size_t)bzi * K;
    outF += (size_t)bzi * (size_t)M * N;
  }
  f32x4 acc[MI][NJ];
  #pragma unroll
  for (int i = 0; i < MI; i++)
    #pragma unroll
    for (int j = 0; j < NJ; j++)
      #pragma unroll
      for (int r = 0; r < 4; r++) acc[i][j][r] = 0.0f;

  const int nt = K / 32;              // divisible by 3 for all our launches
  const short* pA[NA];
  const short* pB[NB];
  #pragma unroll
  for (int p = 0; p < NA; ++p)
    pA[p] = A + (size_t)(m0 + p * 64 + w * 16 + lr) * lda + lc;
  #pragma unroll
  for (int p = 0; p < NB; ++p)
    pB[p] = Bt + (size_t)(n0 + p * 64 + w * 16 + lr) * ldb + lc;
  // T2: fragment read slot = c4 ^ s(row)   (row bases all vanish mod 4)
  const int fr = lane & 15, c4 = lane >> 4;
  const int aoff = (wm + fr) * 32 + ((c4 ^ ((fr >> 1) & 3))) * 8;
  const int boff = (wn + fr) * 32 + ((c4 ^ ((fr >> 1) & 3))) * 8;

#define STAGE(SB)                                                              \
  do {                                                                         \
    _Pragma("unroll") for (int p = 0; p < NA; ++p) {                           \
      gload16(pA[p], &As[SB][p * 2048 + w * 512]);                             \
      pA[p] += 32;                                                             \
    }                                                                          \
    _Pragma("unroll") for (int p = 0; p < NB; ++p) {                           \
      gload16(pB[p], &Bs[SB][p * 2048 + w * 512]);                             \
      pB[p] += 32;                                                             \
    }                                                                          \
  } while (0)

#define STEP(CB, SB, DOSTAGE, LAST)                                            \
  do {                                                                         \
    if (LAST) asm volatile("s_waitcnt vmcnt(0)" ::: "memory");                 \
    else      asm volatile("s_waitcnt vmcnt(%0)" :: "n"(G) : "memory");        \
    __builtin_amdgcn_s_barrier();                                              \
    __builtin_amdgcn_sched_barrier(0);                                         \
    bf16x8 af[MI], bfr[NJ];                                                    \
    _Pragma("unroll") for (int i = 0; i < MI; i++)                             \
      af[i] = *(const bf16x8*)&As[CB][aoff + i * 512];                         \
    _Pragma("unroll") for (int j = 0; j < NJ; j++)                             \
      bfr[j] = *(const bf16x8*)&Bs[CB][boff + j * 512];                        \
    if (DOSTAGE) STAGE(SB);                                                    \
    _Pragma("unroll") for (int i = 0; i < MI; i++)                             \
      _Pragma("unroll") for (int j = 0; j < NJ; j++)                           \
        acc[i][j] = __builtin_amdgcn_mfma_f32_16x16x32_bf16(                   \
            af[i], bfr[j], acc[i][j], 0, 0, 0);                                \
  } while (0)

  STAGE(0);
  STAGE(1);
  const int ntri = nt / 3;
  for (int ti = 0; ti < ntri - 1; ++ti) {
    STEP(0, 2, 1, 0);
    STEP(1, 0, 1, 0);
    STEP(2, 1, 1, 0);
  }
  STEP(0, 2, 1, 0);
  STEP(1, 0, 0, 0);
  STEP(2, 0, 0, 1);
#undef STEP
#undef STAGE

  const int r0 = (lane >> 4) * 4, cl = lane & 15;
  #pragma unroll
  for (int i = 0; i < MI; i++) {
    #pragma unroll
    for (int j = 0; j < NJ; j++) {
      const int gm = m0 + wm + i * 16 + r0;
      const int gn = n0 + wn + j * 16 + cl;
      #pragma unroll
      for (int r = 0; r < 4; r++) {
        const size_t idx = (size_t)(gm + r) * N + gn;
        const float v = acc[i][j][r];
        if constexpr (EPI == 0) {
          outB[idx] = f2bf(v);
        } else if constexpr (EPI == 1) {
          outF[idx] = res[idx] + v;
        } else if constexpr (EPI == 2) {
          outB[idx] = f2bf(0.5f * v * (1.0f + erff(v * 0.70710678118f)));
        } else {
          outF[idx] = v;
        }
      }
    }
  }
}

// ---------------- split-K=2 reduce: out = res + sum_z Cp[z] ----------------
__global__ __launch_bounds__(256) void reduce_splitk(
    const float* __restrict__ Cp, const float* __restrict__ res,
    float* __restrict__ out) {
  const size_t i4 = ((size_t)blockIdx.x * 256 + threadIdx.x) * 4;
  float4 a = *(const float4*)(res + i4);
  #pragma unroll
  for (int z = 0; z < 2; ++z) {
    float4 p = *(const float4*)(Cp + (size_t)z * 3145728 + i4);
    a.x += p.x; a.y += p.y; a.z += p.z; a.w += p.w;
  }
  *(float4*)(out + i4) = a;
}

// ---------------- attention partials: cooperative LDS-staged j-window -------
__global__ __launch_bounds__(512) void attn_part8(
    const short* __restrict__ qkv, const short* __restrict__ vT,
    const short* __restrict__ qpr, const short* __restrict__ ktab,
    float* __restrict__ mpart, float* __restrict__ lpart,
    short* __restrict__ Ypart) {
  __shared__ __align__(16) short Ka[2][32 * 136];  // row: [k(64) | ktab(64) | pad8]
  __shared__ __align__(16) short Va[2][64 * 40];   // row d: [v(32) | pad8]
  const int bx = blockIdx.x;
  const int bh = bx / 20;
  const int r = bx % 20;
  int c, sub;
  if (r < 4)        { c = 0; sub = r; }
  else if (r < 8)   { c = 1; sub = r - 4; }
  else if (r < 11)  { c = 2; sub = r - 8; }
  else if (r < 14)  { c = 3; sub = r - 11; }
  else if (r < 16)  { c = 4; sub = r - 14; }
  else if (r < 18)  { c = 5; sub = r - 16; }
  else if (r == 18) { c = 6; sub = 0; }
  else              { c = 7; sub = 0; }
  const int tid = threadIdx.x;
  const int w = tid >> 6;
  const int lane = tid & 63;
  const int li = lane & 31, hi = lane >> 5;
  const int it = 4 * c + sub * 8 + w;
  const bool valid = (it <= 31);
  const int b = bh / 12, h = bh % 12;
  const int I0 = (valid ? it : 31) * 32;
  const int jt0 = 4 * c;
  const int jtmax = valid ? ((it < jt0 + 3) ? it : jt0 + 3) : (jt0 - 1);
  constexpr float SCALE2 = 0.125f * 1.44269504089f;  // 1/sqrt(64) * log2(e)

  const short* kbase = qkv + (size_t)(b * 1024) * 2304 + 768 + h * 64;
  const short* vbase = vT + (size_t)bh * 64 * 1024;

  const int krow = tid >> 4, kch = tid & 15;
  const short* ksrc = (kch < 8) ? (kbase + kch * 8) : (ktab + (kch - 8) * 8);
  const size_t kstr = (kch < 8) ? 2304 : 64;
  const int vrow = tid >> 2, vch = tid & 3;

  int4 kreg, vreg;
  {
    const int J0 = jt0 * 32;
    kreg = *(const int4*)(ksrc + (size_t)(J0 + krow) * kstr);
    if (tid < 256)
      vreg = *(const int4*)(vbase + (size_t)vrow * 1024 + J0 + vch * 8);
  }

  const short* qrow = qkv + (size_t)(b * 1024 + I0 + li) * 2304 + h * 64;
  const short* qprow = qpr + ((size_t)bh * 1024 + I0 + li) * 64;
  bf16x8 qf[8];
  #pragma unroll
  for (int s = 0; s < 4; s++) {
    qf[s]     = *(const bf16x8*)(qrow + s * 16 + hi * 8);
    qf[4 + s] = *(const bf16x8*)(qprow + s * 16 + hi * 8);
  }

  *(int4*)&Ka[0][krow * 136 + kch * 8] = kreg;
  if (tid < 256) *(int4*)&Va[0][vrow * 40 + vch * 8] = vreg;
  __syncthreads();

  float m_run = -1e30f, l_run = 0.0f;
  f32x16 ya0, ya1;
  #pragma unroll
  for (int q = 0; q < 16; q++) { ya0[q] = 0.0f; ya1[q] = 0.0f; }

  for (int t = 0; t < 4; ++t) {
    const int cur = t & 1;
    if (t < 3) {
      const int J0n = (jt0 + t + 1) * 32;
      kreg = *(const int4*)(ksrc + (size_t)(J0n + krow) * kstr);
      if (tid < 256)
        vreg = *(const int4*)(vbase + (size_t)vrow * 1024 + J0n + vch * 8);
    }
    const int jt = jt0 + t;
    if (jt <= jtmax) {
      bf16x8 kf[8];
      #pragma unroll
      for (int s = 0; s < 8; s++)
        kf[s] = *(const bf16x8*)&Ka[cur][li * 136 + s * 16 + hi * 8];
      bf16x8 vc[4];
      #pragma unroll
      for (int s = 0; s < 2; s++) {
        vc[s * 2]     = *(const bf16x8*)&Va[cur][li * 40 + s * 16 + hi * 8];
        vc[s * 2 + 1] = *(const bf16x8*)&Va[cur][(32 + li) * 40 + s * 16 + hi * 8];
      }
      f32x16 sa0, sa1;
      #pragma unroll
      for (int q = 0; q < 16; q++) { sa0[q] = 0.0f; sa1[q] = 0.0f; }
      __builtin_amdgcn_s_setprio(1);
      #pragma unroll
      for (int s = 0; s < 4; s++) {
        sa0 = __builtin_amdgcn_mfma_f32_32x32x16_bf16(kf[2 * s],     qf[2 * s],     sa0, 0, 0, 0);
        sa1 = __builtin_amdgcn_mfma_f32_32x32x16_bf16(kf[2 * s + 1], qf[2 * s + 1], sa1, 0, 0, 0);
      }
      __builtin_amdgcn_s_setprio(0);
      float sv[16];
      float mx = -1e30f;
      if (jt == it) {
        #pragma unroll
        for (int q = 0; q < 16; q++) {
          const int j = (q & 3) + 8 * (q >> 2) + 4 * hi;
          float v = (sa0[q] + sa1[q]) * SCALE2;
          v = (j <= li) ? v : -1e30f;
          sv[q] = v;
          mx = fmaxf(mx, v);
        }
      } else {
        #pragma unroll
        for (int q = 0; q < 16; q++) {
          const float v = (sa0[q] + sa1[q]) * SCALE2;
          sv[q] = v;
          mx = fmaxf(mx, v);
        }
      }
      mx = fmaxf(mx, __shfl_xor(mx, 32));
      float mref = m_run;
      float alpha = 1.0f;
      const bool resc = !__all(mx <= m_run + 11.5f);
      if (resc) {
        mref = fmaxf(m_run, mx);
        alpha = exp2f(m_run - mref);
        m_run = mref;
      }
      float psum = 0.0f;
      unsigned pw[8];
      #pragma unroll
      for (int q = 0; q < 8; q++) {
        const float p0 = exp2f(sv[2 * q] - mref);
        const float p1 = exp2f(sv[2 * q + 1] - mref);
        psum += p0 + p1;
        pw[q] = cvt_pk_bf16(p0, p1);
      }
      psum += __shfl_xor(psum, 32);
      l_run = l_run * alpha + psum;
      if (resc) {
        #pragma unroll
        for (int q = 0; q < 16; q++) {
          const int row = (q & 3) + 8 * (q >> 2) + 4 * hi;
          const float a = __shfl(alpha, row);
          ya0[q] *= a;
          ya1[q] *= a;
        }
      }
      #pragma unroll
      for (int s = 0; s < 2; s++) {
        unsigned a0 = pw[4 * s],     b0 = pw[4 * s + 2];
        unsigned a1 = pw[4 * s + 1], b1 = pw[4 * s + 3];
        asm volatile("v_permlane32_swap_b32 %0, %1" : "+v"(a0), "+v"(b0));
        asm volatile("v_permlane32_swap_b32 %0, %1" : "+v"(a1), "+v"(b1));
        u32x4 t4;
        t4[0] = a0; t4[1] = a1; t4[2] = b0; t4[3] = b1;
        const bf16x8 pf = __builtin_bit_cast(bf16x8, t4);
        __builtin_amdgcn_s_setprio(1);
        ya0 = __builtin_amdgcn_mfma_f32_32x32x16_bf16(pf, vc[s * 2],     ya0, 0, 0, 0);
        ya1 = __builtin_amdgcn_mfma_f32_32x32x16_bf16(pf, vc[s * 2 + 1], ya1, 0, 0, 0);
        __builtin_amdgcn_s_setprio(0);
      }
    }
    if (t < 3) {
      *(int4*)&Ka[cur ^ 1][krow * 136 + kch * 8] = kreg;
      if (tid < 256) *(int4*)&Va[cur ^ 1][vrow * 40 + vch * 8] = vreg;
    }
    __syncthreads();
  }
  if (!valid) return;
  const int task = bh * 144 + it + 30 * c - 2 * c * c;
  if (hi == 0) {
    mpart[(size_t)task * 32 + li] = m_run;
    lpart[(size_t)task * 32 + li] = l_run;
  }
  short* yb = Ypart + (size_t)task * 2048;
  #pragma unroll
  for (int q = 0; q < 16; q++) {
    const int row = (q & 3) + 8 * (q >> 2) + 4 * hi;
    yb[row * 64 + li]      = f2bf(ya0[q]);
    yb[row * 64 + 32 + li] = f2bf(ya1[q]);
  }
}

// ---------------- attention combine: merge <=8 chunks (c-major layout) ------
__global__ __launch_bounds__(256) void attn_combine(
    const float* __restrict__ mpart, const float* __restrict__ lpart,
    const short* __restrict__ Ypart, short* __restrict__ yout) {
  const int blk = blockIdx.x;  // bh*32 + it
  const int it = blk & 31, bh = blk >> 5;
  const int b = bh / 12, h = bh % 12;
  const int g = it >> 2;
  const int nc = g + 1;
  const int row = threadIdx.x >> 3;
  const int c0 = (threadIdx.x & 7) * 8;
  float mv[8], lv[8], wgt[8];
  float m = -1e30f;
  #pragma unroll
  for (int cI = 0; cI < 8; ++cI) {
    const int idx = bh * 144 + it + 30 * cI - 2 * cI * cI;
    mv[cI] = (cI < nc) ? mpart[(size_t)idx * 32 + row] : -1e30f;
    lv[cI] = (cI < nc) ? lpart[(size_t)idx * 32 + row] : 0.0f;
    m = fmaxf(m, mv[cI]);
  }
  float L = 0.0f;
  #pragma unroll
  for (int cI = 0; cI < 8; ++cI) {
    wgt[cI] = exp2f(mv[cI] - m);
    L += lv[cI] * wgt[cI];
  }
  const float inv = 1.0f / L;
  float y[8];
  #pragma unroll
  for (int r = 0; r < 8; r++) y[r] = 0.0f;
  #pragma unroll
  for (int cI = 0; cI < 8; ++cI) {
    if (cI < nc) {
      const int idx = bh * 144 + it + 30 * cI - 2 * cI * cI;
      bf16x8 v = *(const bf16x8*)(Ypart + ((size_t)idx * 32 + row) * 64 + c0);
      #pragma unroll
      for (int r = 0; r < 8; r++) y[r] += bf2f(v[r]) * wgt[cI];
    }
  }
  short* dst = yout + (size_t)(b * 1024 + it * 32 + row) * 768 + h * 64 + c0;
  #pragma unroll
  for (int r = 0; r < 8; r++) dst[r] = f2bf(y[r] * inv);
}

// ---------------- launch ----------------
extern "C" void kernel_launch(void* const* d_in, const int* in_sizes, int n_in,
                              void* d_out, int out_size, void* d_ws, size_t ws_size,
                              hipStream_t stream) {
  const float* x       = (const float*)d_in[0];
  const float* ln1_w   = (const float*)d_in[1];
  const float* w_attn  = (const float*)d_in[2];
  // d_in[3] = w_pos (dead code in reference)
  const float* w_cproj = (const float*)d_in[4];
  const float* ln2_w   = (const float*)d_in[5];
  const float* w_fc    = (const float*)d_in[6];
  const float* w_mproj = (const float*)d_in[7];
  float* out = (float*)d_out;
  char* ws = (char*)d_ws;

  short* wT_attn  = (short*)(ws + 0);          // [2304][768]
  short* wT_cproj = (short*)(ws + 3538944);    // [768][768]
  short* wT_fc    = (short*)(ws + 4718592);    // [3072][768]
  short* wT_mproj = (short*)(ws + 9437184);    // [768][3072]
  short* ktab     = (short*)(ws + 14155776);   // [1024][64] bf16 (128KB)
  short* h_bf     = (short*)(ws + 14417920);   // [4096][768]; reused as qpr
  short* qpr      = (short*)(ws + 14417920);   // [48*1024][64] (h_bf dead then)
  short* qkv_bf   = (short*)(ws + 20709376);   // [4096][2304]
  short* vT       = (short*)(ws + 39583744);   // [48][64][1024]
  short* y_att    = (short*)(ws + 45875200);   // [4096][768]
  short* h2_bf    = (short*)(ws + 52166656);   // [4096][768]
  short* hfc_bf   = (short*)(ws + 58458112);   // [4096][3072]
  // attention partials alias the (not-yet-live) MLP buffers:
  float* mpart = (float*)(ws + 52166656);      // [6912][32] f32
  float* lpart = (float*)(ws + 53051392);      // [6912][32] f32
  short* Ypart = (short*)(ws + 53936128);      // [6912][32][64] bf16 (28.3MB)
  // mproj split-K=2 partials alias dead qkv_bf+vT: 2 x [4096][768] f32
  float* Cpart = (float*)(ws + 20709376);      // 25165824 B exactly

  // weight prep
  wtrans_all<<<6912, 256, 0, stream>>>(w_attn, w_cproj, w_fc, w_mproj,
                                       wT_attn, wT_cproj, wT_fc, wT_mproj);

  // attention branch
  ln_kernel<<<4096, 256, 0, stream>>>(x, ln1_w, h_bf);
  gemm3u<0, 64, 128><<<dim3(18, 64), 256, 0, stream>>>(
      h_bf, wT_attn, nullptr, nullptr, qkv_bf, 4096, 2304, 768, 768, 768);
  qv_kernel<<<6912, 256, 0, stream>>>(qkv_bf, qpr, ktab, vT);
  attn_part8<<<960, 512, 0, stream>>>(qkv_bf, vT, qpr, ktab, mpart, lpart, Ypart);
  attn_combine<<<1536, 256, 0, stream>>>(mpart, lpart, Ypart, y_att);
  gemm3u<1, 64, 64><<<dim3(12, 64), 256, 0, stream>>>(
      y_att, wT_cproj, x, out, nullptr, 4096, 768, 768, 768, 768);
  // MLP branch
  ln_kernel<<<4096, 256, 0, stream>>>(out, ln2_w, h2_bf);
  gemm3u<2, 64, 128><<<dim3(24, 64), 256, 0, stream>>>(
      h2_bf, wT_fc, nullptr, nullptr, hfc_bf, 4096, 3072, 768, 768, 768);
  // mproj: split-K=2 (qkv_bf/vT are dead by now; Cpart aliases them)
  gemm3u<3, 64, 128><<<dim3(6, 64, 2), 256, 0, stream>>>(
      hfc_bf, wT_mproj, nullptr, Cpart, nullptr, 4096, 768, 1536, 3072, 3072);
  reduce_splitk<<<3072, 256, 0, stream>>>(Cpart, out, out);
}

// Round 15
// 188.638 us; speedup vs baseline: 1.1062x; 1.1062x over previous
//
#include <hip/hip_runtime.h>
#include <math.h>

typedef __attribute__((ext_vector_type(8))) short bf16x8;
typedef __attribute__((ext_vector_type(4))) float f32x4;
typedef __attribute__((ext_vector_type(16))) float f32x16;
typedef __attribute__((ext_vector_type(4))) unsigned u32x4;

__device__ inline short f2bf(float f) {
  unsigned u = __builtin_bit_cast(unsigned, f);
  u = u + 0x7fffu + ((u >> 16) & 1u);
  return (short)(u >> 16);
}
__device__ inline float bf2f(short s) {
  return __builtin_bit_cast(float, ((unsigned)(unsigned short)s) << 16);
}
__device__ inline unsigned cvt_pk_bf16(float lo, float hi) {
  unsigned r;
  asm("v_cvt_pk_bf16_f32 %0, %1, %2" : "=v"(r) : "v"(lo), "v"(hi));
  return r;
}

// async global->LDS, 16B per lane. lds base must be wave-uniform.
__device__ inline void gload16(const short* g, const short* l) {
  __builtin_amdgcn_global_load_lds(
      (const __attribute__((address_space(1))) unsigned*)g,
      (__attribute__((address_space(3))) unsigned*)(short*)l, 16, 0, 0);
}

// ----- prep A: 4 weight transposes fp32[K,N]->bf16[N,K]  +  ln1 (folded) ----
// blocks [0,6912): transposes; [6912,11008): LayerNorm1 rows (independent).
__global__ __launch_bounds__(256) void wtrans_all(
    const float* __restrict__ wa, const float* __restrict__ wc,
    const float* __restrict__ wf, const float* __restrict__ wm,
    short* __restrict__ oa, short* __restrict__ oc,
    short* __restrict__ of, short* __restrict__ om,
    const float* __restrict__ x, const float* __restrict__ ln1_w,
    short* __restrict__ h_bf) {
  __shared__ float tile[32][33];
  int blk = blockIdx.x;
  const int tid = threadIdx.x;
  if (blk >= 6912) {
    // ---- LayerNorm1 row ----
    const int row = blk - 6912;
    const float* xr = x + (size_t)row * 768;
    float v0 = xr[tid], v1 = xr[tid + 256], v2 = xr[tid + 512];
    float s = v0 + v1 + v2;
    #pragma unroll
    for (int o = 1; o < 64; o <<= 1) s += __shfl_xor(s, o);
    __shared__ float red[8];
    const int wv = tid >> 6;
    if ((tid & 63) == 0) red[wv] = s;
    __syncthreads();
    const float mean = (red[0] + red[1] + red[2] + red[3]) * (1.0f / 768.0f);
    v0 -= mean; v1 -= mean; v2 -= mean;
    float q = v0 * v0 + v1 * v1 + v2 * v2;
    #pragma unroll
    for (int o = 1; o < 64; o <<= 1) q += __shfl_xor(q, o);
    if ((tid & 63) == 0) red[4 + wv] = q;
    __syncthreads();
    const float var = (red[4] + red[5] + red[6] + red[7]) * (1.0f / 768.0f);
    const float inv = 1.0f / sqrtf(var + 1e-5f);
    h_bf[(size_t)row * 768 + tid]       = f2bf(v0 * inv * ln1_w[tid]);
    h_bf[(size_t)row * 768 + tid + 256] = f2bf(v1 * inv * ln1_w[tid + 256]);
    h_bf[(size_t)row * 768 + tid + 512] = f2bf(v2 * inv * ln1_w[tid + 512]);
    return;
  }
  const float* in; short* out; int K, N, bx;
  if (blk < 1728)      { in = wa; out = oa; K = 768;  N = 2304; bx = 72; }
  else if (blk < 2304) { blk -= 1728; in = wc; out = oc; K = 768;  N = 768;  bx = 24; }
  else if (blk < 4608) { blk -= 2304; in = wf; out = of; K = 768;  N = 3072; bx = 96; }
  else                 { blk -= 4608; in = wm; out = om; K = 3072; N = 768;  bx = 24; }
  const int n0 = (blk % bx) * 32, k0 = (blk / bx) * 32;
  const int tx = tid & 31, ty = tid >> 5;
  #pragma unroll
  for (int r = ty; r < 32; r += 8)
    tile[r][tx] = in[(size_t)(k0 + r) * N + n0 + tx];
  __syncthreads();
  #pragma unroll
  for (int r = ty; r < 32; r += 8)
    out[(size_t)(n0 + r) * K + k0 + tx] = f2bf(tile[tx][r]);
}

// ------- merged prep: blocks [0,768) qprime VECTORIZED; [768,1536) vtrans ---
// qprime: 4 threads/row, 8 contiguous cc each; bf16x8 loads/stores.
__global__ __launch_bounds__(256) void qv_kernel(
    const short* __restrict__ qkv, short* __restrict__ qpr,
    short* __restrict__ ktab, short* __restrict__ vT) {
  __shared__ short tile[64][65];
  if (blockIdx.x < 768) {
    const int idx = blockIdx.x * 256 + threadIdx.x;  // [0, 196608)
    const int row = idx >> 2;            // bh*1024 + i
    const int cc0 = (idx & 3) * 8;
    const int i = row & 1023, bh = row >> 10;
    const int b = bh / 12, h = bh % 12;
    const short* q = qkv + (size_t)(b * 1024 + i) * 2304 + h * 64;
    const bf16x8 q8s = *(const bf16x8*)(q + cc0);
    const bf16x8 q8c = *(const bf16x8*)(q + 32 + cc0);
    bf16x8 o1, o2, kc, ks;
    #pragma unroll
    for (int j = 0; j < 8; ++j) {
      const int cc = cc0 + j;
      const float invf = exp2f(-(float)cc * (13.287712379549449f / 32.0f));
      const float ang = (float)i * invf;
      float si, co;
      __sincosf(ang, &si, &co);
      const float qs = bf2f(q8s[j]), qc = bf2f(q8c[j]);
      o1[j] = f2bf(qs * si + qc * co);
      o2[j] = f2bf(qc * si - qs * co);
      kc[j] = f2bf(co);
      ks[j] = f2bf(si);
    }
    *(bf16x8*)(qpr + (size_t)row * 64 + cc0)      = o1;
    *(bf16x8*)(qpr + (size_t)row * 64 + 32 + cc0) = o2;
    if (bh == 0) {
      *(bf16x8*)(ktab + i * 64 + cc0)      = kc;
      *(bf16x8*)(ktab + i * 64 + 32 + cc0) = ks;
    }
  } else {
    const int blk = blockIdx.x - 768;
    const int bh = blk >> 4, t0 = (blk & 15) * 64;
    const int b = bh / 12, h = bh % 12;
    const int tx = threadIdx.x & 63, ty = threadIdx.x >> 6;
    const short* src = qkv + (size_t)(b * 1024 + t0) * 2304 + 1536 + h * 64;
    #pragma unroll
    for (int r = ty; r < 64; r += 4)
      tile[r][tx] = src[(size_t)r * 2304 + tx];
    __syncthreads();
    short* dst = vT + (size_t)bh * 64 * 1024 + t0;
    #pragma unroll
    for (int r = ty; r < 64; r += 4)
      dst[(size_t)r * 1024 + tx] = tile[tx][r];
  }
}

// ---------------- LayerNorm fp32 row(768) -> bf16 (used for ln2) ------------
__global__ __launch_bounds__(256) void ln_kernel(
    const float* __restrict__ x, const float* __restrict__ w,
    short* __restrict__ out) {
  const int row = blockIdx.x, tid = threadIdx.x;
  const float* xr = x + (size_t)row * 768;
  float v0 = xr[tid], v1 = xr[tid + 256], v2 = xr[tid + 512];
  float s = v0 + v1 + v2;
  #pragma unroll
  for (int o = 1; o < 64; o <<= 1) s += __shfl_xor(s, o);
  __shared__ float red[8];
  const int wv = tid >> 6;
  if ((tid & 63) == 0) red[wv] = s;
  __syncthreads();
  const float mean = (red[0] + red[1] + red[2] + red[3]) * (1.0f / 768.0f);
  v0 -= mean; v1 -= mean; v2 -= mean;
  float q = v0 * v0 + v1 * v1 + v2 * v2;
  #pragma unroll
  for (int o = 1; o < 64; o <<= 1) q += __shfl_xor(q, o);
  if ((tid & 63) == 0) red[4 + wv] = q;
  __syncthreads();
  const float var = (red[4] + red[5] + red[6] + red[7]) * (1.0f / 768.0f);
  const float inv = 1.0f / sqrtf(var + 1e-5f);
  out[(size_t)row * 768 + tid]       = f2bf(v0 * inv * w[tid]);
  out[(size_t)row * 768 + tid + 256] = f2bf(v1 * inv * w[tid + 256]);
  out[(size_t)row * 768 + tid + 512] = f2bf(v2 * inv * w[tid + 512]);
}

// ======= GEMM: 3-stage ring + T2 XOR chunk-swizzle (conflict-free reads) ====
// C[M,N] = A[M,K] x Bt[N,K], bf16 in, f32 acc. BK=32. nt MUST be %3==0.
// R13-proven config: 128x128 (big GEMMs), conflicts 0, counted vmcnt,
// pointer-increment addressing, T1 XCD swizzle.
// EPI 0: bf16 store  1: f32 out=res+acc  2: bf16 gelu  3: f32 split-K partial
template <int EPI, int BM, int BN>
__global__ __launch_bounds__(256) void gemm3u(
    const short* __restrict__ A, const short* __restrict__ Bt,
    const float* __restrict__ res, float* __restrict__ outF,
    short* __restrict__ outB, int M, int N, int K, int lda, int ldb) {
  __shared__ __align__(16) short As[3][BM * 32];
  __shared__ __align__(16) short Bs[3][BN * 32];
  constexpr int WM = BM / 2, WN = BN / 2;
  constexpr int MI = WM / 16, NJ = WN / 16;
  constexpr int NA = BM / 64, NB = BN / 64;
  constexpr int G = NA + NB;          // gloads per stage per wave
  const int tid = threadIdx.x;
  const int w = tid >> 6, lane = tid & 63;
  // T1 XCD-aware bijective swizzle (x-fastest dispatch order)
  const int gx = gridDim.x, gy = gridDim.y;
  const int nwg = gx * gy * gridDim.z;
  const int lin = blockIdx.x + gx * (blockIdx.y + gy * blockIdx.z);
  const int wg = (lin & 7) * (nwg >> 3) + (lin >> 3);
  const int bxi = wg % gx;
  const int tmp = wg / gx;
  const int byi = tmp % gy, bzi = tmp / gy;
  const int m0 = byi * BM, n0 = bxi * BN;
  const int wm = (w >> 1) * WM, wn = (w & 1) * WN;
  const int lr = lane >> 2;
  // T2: source chunk pre-swizzle  slot -> global chunk (slot ^ s(row))
  const int lc = (((lane & 3) ^ ((lr >> 1) & 3))) * 8;
  if constexpr (EPI == 3) {
    A += (size_t)bzi * K;
    Bt += (size_t)bzi * K;
    outF += (size_t)bzi * (size_t)M * N;
  }
  f32x4 acc[MI][NJ];
  #pragma unroll
  for (int i = 0; i < MI; i++)
    #pragma unroll
    for (int j = 0; j < NJ; j++)
      #pragma unroll
      for (int r = 0; r < 4; r++) acc[i][j][r] = 0.0f;

  const int nt = K / 32;              // divisible by 3 for all our launches
  const short* pA[NA];
  const short* pB[NB];
  #pragma unroll
  for (int p = 0; p < NA; ++p)
    pA[p] = A + (size_t)(m0 + p * 64 + w * 16 + lr) * lda + lc;
  #pragma unroll
  for (int p = 0; p < NB; ++p)
    pB[p] = Bt + (size_t)(n0 + p * 64 + w * 16 + lr) * ldb + lc;
  // T2: fragment read slot = c4 ^ s(row)   (row bases all vanish mod 4)
  const int fr = lane & 15, c4 = lane >> 4;
  const int aoff = (wm + fr) * 32 + ((c4 ^ ((fr >> 1) & 3))) * 8;
  const int boff = (wn + fr) * 32 + ((c4 ^ ((fr >> 1) & 3))) * 8;

#define STAGE(SB)                                                              \
  do {                                                                         \
    _Pragma("unroll") for (int p = 0; p < NA; ++p) {                           \
      gload16(pA[p], &As[SB][p * 2048 + w * 512]);                             \
      pA[p] += 32;                                                             \
    }                                                                          \
    _Pragma("unroll") for (int p = 0; p < NB; ++p) {                           \
      gload16(pB[p], &Bs[SB][p * 2048 + w * 512]);                             \
      pB[p] += 32;                                                             \
    }                                                                          \
  } while (0)

#define STEP(CB, SB, DOSTAGE, LAST)                                            \
  do {                                                                         \
    if (LAST) asm volatile("s_waitcnt vmcnt(0)" ::: "memory");                 \
    else      asm volatile("s_waitcnt vmcnt(%0)" :: "n"(G) : "memory");        \
    __builtin_amdgcn_s_barrier();                                              \
    __builtin_amdgcn_sched_barrier(0);                                         \
    bf16x8 af[MI], bfr[NJ];                                                    \
    _Pragma("unroll") for (int i = 0; i < MI; i++)                             \
      af[i] = *(const bf16x8*)&As[CB][aoff + i * 512];                         \
    _Pragma("unroll") for (int j = 0; j < NJ; j++)                             \
      bfr[j] = *(const bf16x8*)&Bs[CB][boff + j * 512];                        \
    if (DOSTAGE) STAGE(SB);                                                    \
    _Pragma("unroll") for (int i = 0; i < MI; i++)                             \
      _Pragma("unroll") for (int j = 0; j < NJ; j++)                           \
        acc[i][j] = __builtin_amdgcn_mfma_f32_16x16x32_bf16(                   \
            af[i], bfr[j], acc[i][j], 0, 0, 0);                                \
  } while (0)

  STAGE(0);
  STAGE(1);
  const int ntri = nt / 3;
  for (int ti = 0; ti < ntri - 1; ++ti) {
    STEP(0, 2, 1, 0);
    STEP(1, 0, 1, 0);
    STEP(2, 1, 1, 0);
  }
  STEP(0, 2, 1, 0);
  STEP(1, 0, 0, 0);
  STEP(2, 0, 0, 1);
#undef STEP
#undef STAGE

  const int r0 = (lane >> 4) * 4, cl = lane & 15;
  #pragma unroll
  for (int i = 0; i < MI; i++) {
    #pragma unroll
    for (int j = 0; j < NJ; j++) {
      const int gm = m0 + wm + i * 16 + r0;
      const int gn = n0 + wn + j * 16 + cl;
      #pragma unroll
      for (int r = 0; r < 4; r++) {
        const size_t idx = (size_t)(gm + r) * N + gn;
        const float v = acc[i][j][r];
        if constexpr (EPI == 0) {
          outB[idx] = f2bf(v);
        } else if constexpr (EPI == 1) {
          outF[idx] = res[idx] + v;
        } else if constexpr (EPI == 2) {
          outB[idx] = f2bf(0.5f * v * (1.0f + erff(v * 0.70710678118f)));
        } else {
          outF[idx] = v;
        }
      }
    }
  }
}

// ---------------- split-K=2 reduce: out = res + sum_z Cp[z] ----------------
__global__ __launch_bounds__(256) void reduce_splitk(
    const float* __restrict__ Cp, const float* __restrict__ res,
    float* __restrict__ out) {
  const size_t i4 = ((size_t)blockIdx.x * 256 + threadIdx.x) * 4;
  float4 a = *(const float4*)(res + i4);
  #pragma unroll
  for (int z = 0; z < 2; ++z) {
    float4 p = *(const float4*)(Cp + (size_t)z * 3145728 + i4);
    a.x += p.x; a.y += p.y; a.z += p.z; a.w += p.w;
  }
  *(float4*)(out + i4) = a;
}

// ---------------- attention partials: cooperative LDS-staged j-window -------
__global__ __launch_bounds__(512) void attn_part8(
    const short* __restrict__ qkv, const short* __restrict__ vT,
    const short* __restrict__ qpr, const short* __restrict__ ktab,
    float* __restrict__ mpart, float* __restrict__ lpart,
    short* __restrict__ Ypart) {
  __shared__ __align__(16) short Ka[2][32 * 136];  // row: [k(64) | ktab(64) | pad8]
  __shared__ __align__(16) short Va[2][64 * 40];   // row d: [v(32) | pad8]
  const int bx = blockIdx.x;
  const int bh = bx / 20;
  const int r = bx % 20;
  int c, sub;
  if (r < 4)        { c = 0; sub = r; }
  else if (r < 8)   { c = 1; sub = r - 4; }
  else if (r < 11)  { c = 2; sub = r - 8; }
  else if (r < 14)  { c = 3; sub = r - 11; }
  else if (r < 16)  { c = 4; sub = r - 14; }
  else if (r < 18)  { c = 5; sub = r - 16; }
  else if (r == 18) { c = 6; sub = 0; }
  else              { c = 7; sub = 0; }
  const int tid = threadIdx.x;
  const int w = tid >> 6;
  const int lane = tid & 63;
  const int li = lane & 31, hi = lane >> 5;
  const int it = 4 * c + sub * 8 + w;
  const bool valid = (it <= 31);
  const int b = bh / 12, h = bh % 12;
  const int I0 = (valid ? it : 31) * 32;
  const int jt0 = 4 * c;
  const int jtmax = valid ? ((it < jt0 + 3) ? it : jt0 + 3) : (jt0 - 1);
  constexpr float SCALE2 = 0.125f * 1.44269504089f;  // 1/sqrt(64) * log2(e)

  const short* kbase = qkv + (size_t)(b * 1024) * 2304 + 768 + h * 64;
  const short* vbase = vT + (size_t)bh * 64 * 1024;

  const int krow = tid >> 4, kch = tid & 15;
  const short* ksrc = (kch < 8) ? (kbase + kch * 8) : (ktab + (kch - 8) * 8);
  const size_t kstr = (kch < 8) ? 2304 : 64;
  const int vrow = tid >> 2, vch = tid & 3;

  int4 kreg, vreg;
  {
    const int J0 = jt0 * 32;
    kreg = *(const int4*)(ksrc + (size_t)(J0 + krow) * kstr);
    if (tid < 256)
      vreg = *(const int4*)(vbase + (size_t)vrow * 1024 + J0 + vch * 8);
  }

  const short* qrow = qkv + (size_t)(b * 1024 + I0 + li) * 2304 + h * 64;
  const short* qprow = qpr + ((size_t)bh * 1024 + I0 + li) * 64;
  bf16x8 qf[8];
  #pragma unroll
  for (int s = 0; s < 4; s++) {
    qf[s]     = *(const bf16x8*)(qrow + s * 16 + hi * 8);
    qf[4 + s] = *(const bf16x8*)(qprow + s * 16 + hi * 8);
  }

  *(int4*)&Ka[0][krow * 136 + kch * 8] = kreg;
  if (tid < 256) *(int4*)&Va[0][vrow * 40 + vch * 8] = vreg;
  __syncthreads();

  float m_run = -1e30f, l_run = 0.0f;
  f32x16 ya0, ya1;
  #pragma unroll
  for (int q = 0; q < 16; q++) { ya0[q] = 0.0f; ya1[q] = 0.0f; }

  for (int t = 0; t < 4; ++t) {
    const int cur = t & 1;
    if (t < 3) {
      const int J0n = (jt0 + t + 1) * 32;
      kreg = *(const int4*)(ksrc + (size_t)(J0n + krow) * kstr);
      if (tid < 256)
        vreg = *(const int4*)(vbase + (size_t)vrow * 1024 + J0n + vch * 8);
    }
    const int jt = jt0 + t;
    if (jt <= jtmax) {
      bf16x8 kf[8];
      #pragma unroll
      for (int s = 0; s < 8; s++)
        kf[s] = *(const bf16x8*)&Ka[cur][li * 136 + s * 16 + hi * 8];
      bf16x8 vc[4];
      #pragma unroll
      for (int s = 0; s < 2; s++) {
        vc[s * 2]     = *(const bf16x8*)&Va[cur][li * 40 + s * 16 + hi * 8];
        vc[s * 2 + 1] = *(const bf16x8*)&Va[cur][(32 + li) * 40 + s * 16 + hi * 8];
      }
      f32x16 sa0, sa1;
      #pragma unroll
      for (int q = 0; q < 16; q++) { sa0[q] = 0.0f; sa1[q] = 0.0f; }
      __builtin_amdgcn_s_setprio(1);
      #pragma unroll
      for (int s = 0; s < 4; s++) {
        sa0 = __builtin_amdgcn_mfma_f32_32x32x16_bf16(kf[2 * s],     qf[2 * s],     sa0, 0, 0, 0);
        sa1 = __builtin_amdgcn_mfma_f32_32x32x16_bf16(kf[2 * s + 1], qf[2 * s + 1], sa1, 0, 0, 0);
      }
      __builtin_amdgcn_s_setprio(0);
      float sv[16];
      float mx = -1e30f;
      if (jt == it) {
        #pragma unroll
        for (int q = 0; q < 16; q++) {
          const int j = (q & 3) + 8 * (q >> 2) + 4 * hi;
          float v = (sa0[q] + sa1[q]) * SCALE2;
          v = (j <= li) ? v : -1e30f;
          sv[q] = v;
          mx = fmaxf(mx, v);
        }
      } else {
        #pragma unroll
        for (int q = 0; q < 16; q++) {
          const float v = (sa0[q] + sa1[q]) * SCALE2;
          sv[q] = v;
          mx = fmaxf(mx, v);
        }
      }
      mx = fmaxf(mx, __shfl_xor(mx, 32));
      float mref = m_run;
      float alpha = 1.0f;
      const bool resc = !__all(mx <= m_run + 11.5f);
      if (resc) {
        mref = fmaxf(m_run, mx);
        alpha = exp2f(m_run - mref);
        m_run = mref;
      }
      float psum = 0.0f;
      unsigned pw[8];
      #pragma unroll
      for (int q = 0; q < 8; q++) {
        const float p0 = exp2f(sv[2 * q] - mref);
        const float p1 = exp2f(sv[2 * q + 1] - mref);
        psum += p0 + p1;
        pw[q] = cvt_pk_bf16(p0, p1);
      }
      psum += __shfl_xor(psum, 32);
      l_run = l_run * alpha + psum;
      if (resc) {
        #pragma unroll
        for (int q = 0; q < 16; q++) {
          const int row = (q & 3) + 8 * (q >> 2) + 4 * hi;
          const float a = __shfl(alpha, row);
          ya0[q] *= a;
          ya1[q] *= a;
        }
      }
      #pragma unroll
      for (int s = 0; s < 2; s++) {
        unsigned a0 = pw[4 * s],     b0 = pw[4 * s + 2];
        unsigned a1 = pw[4 * s + 1], b1 = pw[4 * s + 3];
        asm volatile("v_permlane32_swap_b32 %0, %1" : "+v"(a0), "+v"(b0));
        asm volatile("v_permlane32_swap_b32 %0, %1" : "+v"(a1), "+v"(b1));
        u32x4 t4;
        t4[0] = a0; t4[1] = a1; t4[2] = b0; t4[3] = b1;
        const bf16x8 pf = __builtin_bit_cast(bf16x8, t4);
        __builtin_amdgcn_s_setprio(1);
        ya0 = __builtin_amdgcn_mfma_f32_32x32x16_bf16(pf, vc[s * 2],     ya0, 0, 0, 0);
        ya1 = __builtin_amdgcn_mfma_f32_32x32x16_bf16(pf, vc[s * 2 + 1], ya1, 0, 0, 0);
        __builtin_amdgcn_s_setprio(0);
      }
    }
    if (t < 3) {
      *(int4*)&Ka[cur ^ 1][krow * 136 + kch * 8] = kreg;
      if (tid < 256) *(int4*)&Va[cur ^ 1][vrow * 40 + vch * 8] = vreg;
    }
    __syncthreads();
  }
  if (!valid) return;
  const int task = bh * 144 + it + 30 * c - 2 * c * c;
  if (hi == 0) {
    mpart[(size_t)task * 32 + li] = m_run;
    lpart[(size_t)task * 32 + li] = l_run;
  }
  short* yb = Ypart + (size_t)task * 2048;
  #pragma unroll
  for (int q = 0; q < 16; q++) {
    const int row = (q & 3) + 8 * (q >> 2) + 4 * hi;
    yb[row * 64 + li]      = f2bf(ya0[q]);
    yb[row * 64 + 32 + li] = f2bf(ya1[q]);
  }
}

// ---------------- attention combine: merge <=8 chunks (c-major layout) ------
__global__ __launch_bounds__(256) void attn_combine(
    const float* __restrict__ mpart, const float* __restrict__ lpart,
    const short* __restrict__ Ypart, short* __restrict__ yout) {
  const int blk = blockIdx.x;  // bh*32 + it
  const int it = blk & 31, bh = blk >> 5;
  const int b = bh / 12, h = bh % 12;
  const int g = it >> 2;
  const int nc = g + 1;
  const int row = threadIdx.x >> 3;
  const int c0 = (threadIdx.x & 7) * 8;
  float mv[8], lv[8], wgt[8];
  float m = -1e30f;
  #pragma unroll
  for (int cI = 0; cI < 8; ++cI) {
    const int idx = bh * 144 + it + 30 * cI - 2 * cI * cI;
    mv[cI] = (cI < nc) ? mpart[(size_t)idx * 32 + row] : -1e30f;
    lv[cI] = (cI < nc) ? lpart[(size_t)idx * 32 + row] : 0.0f;
    m = fmaxf(m, mv[cI]);
  }
  float L = 0.0f;
  #pragma unroll
  for (int cI = 0; cI < 8; ++cI) {
    wgt[cI] = exp2f(mv[cI] - m);
    L += lv[cI] * wgt[cI];
  }
  const float inv = 1.0f / L;
  float y[8];
  #pragma unroll
  for (int r = 0; r < 8; r++) y[r] = 0.0f;
  #pragma unroll
  for (int cI = 0; cI < 8; ++cI) {
    if (cI < nc) {
      const int idx = bh * 144 + it + 30 * cI - 2 * cI * cI;
      bf16x8 v = *(const bf16x8*)(Ypart + ((size_t)idx * 32 + row) * 64 + c0);
      #pragma unroll
      for (int r = 0; r < 8; r++) y[r] += bf2f(v[r]) * wgt[cI];
    }
  }
  short* dst = yout + (size_t)(b * 1024 + it * 32 + row) * 768 + h * 64 + c0;
  #pragma unroll
  for (int r = 0; r < 8; r++) dst[r] = f2bf(y[r] * inv);
}

// ---------------- launch ----------------
extern "C" void kernel_launch(void* const* d_in, const int* in_sizes, int n_in,
                              void* d_out, int out_size, void* d_ws, size_t ws_size,
                              hipStream_t stream) {
  const float* x       = (const float*)d_in[0];
  const float* ln1_w   = (const float*)d_in[1];
  const float* w_attn  = (const float*)d_in[2];
  // d_in[3] = w_pos (dead code in reference)
  const float* w_cproj = (const float*)d_in[4];
  const float* ln2_w   = (const float*)d_in[5];
  const float* w_fc    = (const float*)d_in[6];
  const float* w_mproj = (const float*)d_in[7];
  float* out = (float*)d_out;
  char* ws = (char*)d_ws;

  short* wT_attn  = (short*)(ws + 0);          // [2304][768]
  short* wT_cproj = (short*)(ws + 3538944);    // [768][768]
  short* wT_fc    = (short*)(ws + 4718592);    // [3072][768]
  short* wT_mproj = (short*)(ws + 9437184);    // [768][3072]
  short* ktab     = (short*)(ws + 14155776);   // [1024][64] bf16 (128KB)
  short* h_bf     = (short*)(ws + 14417920);   // [4096][768]; reused as qpr
  short* qpr      = (short*)(ws + 14417920);   // [48*1024][64] (h_bf dead then)
  short* qkv_bf   = (short*)(ws + 20709376);   // [4096][2304]
  short* vT       = (short*)(ws + 39583744);   // [48][64][1024]
  short* y_att    = (short*)(ws + 45875200);   // [4096][768]
  short* h2_bf    = (short*)(ws + 52166656);   // [4096][768]
  short* hfc_bf   = (short*)(ws + 58458112);   // [4096][3072]
  // attention partials alias the (not-yet-live) MLP buffers:
  float* mpart = (float*)(ws + 52166656);      // [6912][32] f32
  float* lpart = (float*)(ws + 53051392);      // [6912][32] f32
  short* Ypart = (short*)(ws + 53936128);      // [6912][32][64] bf16 (28.3MB)
  // mproj split-K=2 partials alias dead qkv_bf+vT: 2 x [4096][768] f32
  float* Cpart = (float*)(ws + 20709376);      // 25165824 B exactly

  // weight prep + ln1 (independent work, one launch)
  wtrans_all<<<11008, 256, 0, stream>>>(w_attn, w_cproj, w_fc, w_mproj,
                                        wT_attn, wT_cproj, wT_fc, wT_mproj,
                                        x, ln1_w, h_bf);

  // attention branch
  gemm3u<0, 128, 128><<<dim3(18, 32), 256, 0, stream>>>(
      h_bf, wT_attn, nullptr, nullptr, qkv_bf, 4096, 2304, 768, 768, 768);
  qv_kernel<<<1536, 256, 0, stream>>>(qkv_bf, qpr, ktab, vT);
  attn_part8<<<960, 512, 0, stream>>>(qkv_bf, vT, qpr, ktab, mpart, lpart, Ypart);
  attn_combine<<<1536, 256, 0, stream>>>(mpart, lpart, Ypart, y_att);
  gemm3u<1, 64, 64><<<dim3(12, 64), 256, 0, stream>>>(
      y_att, wT_cproj, x, out, nullptr, 4096, 768, 768, 768, 768);
  // MLP branch
  ln_kernel<<<4096, 256, 0, stream>>>(out, ln2_w, h2_bf);
  gemm3u<2, 128, 128><<<dim3(24, 32), 256, 0, stream>>>(
      h2_bf, wT_fc, nullptr, nullptr, hfc_bf, 4096, 3072, 768, 768, 768);
  // mproj: split-K=2 (qkv_bf/vT are dead by now; Cpart aliases them)
  gemm3u<3, 128, 64><<<dim3(12, 32, 2), 256, 0, stream>>>(
      hfc_bf, wT_mproj, nullptr, Cpart, nullptr, 4096, 768, 1536, 3072, 3072);
  reduce_splitk<<<3072, 256, 0, stream>>>(Cpart, out, out);
}